// Round 1
// baseline (1173.659 us; speedup 1.0000x reference)
//
#include <hip/hip_runtime.h>
#include <stdint.h>

typedef unsigned int u32;
typedef unsigned long long u64;

#define BROWS 32
#define NPTS  262144          // 2^18
#define LOG_NPTS 18
#define NBUCK 8192            // buckets per row, mean occupancy = 32
#define LOG_NBUCK 13
#define TOTAL (BROWS * NPTS)  // 8388608
#define CAP 128               // per-bucket capacity for the wave sort

__device__ __forceinline__ u32 bucket_of(float z0) {
    u32 b = (u32)(z0 * (float)NBUCK);
    return (b >= NBUCK) ? (NBUCK - 1) : b;
}

__global__ void hist_kernel(const float* __restrict__ z, u32* __restrict__ counts) {
    int stride = gridDim.x * blockDim.x;
    for (int e = blockIdx.x * blockDim.x + threadIdx.x; e < TOTAL; e += stride) {
        float z0 = z[(size_t)e * 3];
        u32 b = bucket_of(z0);
        u32 r = (u32)e >> LOG_NPTS;
        atomicAdd(&counts[(r << LOG_NBUCK) + b], 1u);
    }
}

__global__ void scan_kernel(const u32* __restrict__ counts,
                            u32* __restrict__ offsets,
                            u32* __restrict__ cursors) {
    int r = blockIdx.x;
    const u32* c = counts + ((size_t)r << LOG_NBUCK);
    u32* o   = offsets + ((size_t)r << LOG_NBUCK);
    u32* cur = cursors + ((size_t)r << LOG_NBUCK);
    int t = threadIdx.x;              // 256 threads, 32 buckets each
    int base = t * 32;
    u32 loc[32];
    u32 s = 0;
    for (int k = 0; k < 32; ++k) { loc[k] = s; s += c[base + k]; }
    __shared__ u32 lsum[256];
    lsum[t] = s;
    __syncthreads();
    u32 own = s;
    for (int off = 1; off < 256; off <<= 1) {
        u32 v = (t >= off) ? lsum[t - off] : 0;
        __syncthreads();
        lsum[t] += v;
        __syncthreads();
    }
    u32 ex = lsum[t] - own;           // exclusive prefix of this thread's chunk
    for (int k = 0; k < 32; ++k) {
        u32 val = ex + loc[k];
        o[base + k] = val;
        cur[base + k] = val;
    }
}

__global__ void scatter_kernel(const float* __restrict__ z,
                               u32* __restrict__ cursors,
                               u32* __restrict__ recIdx) {
    int stride = gridDim.x * blockDim.x;
    for (int e = blockIdx.x * blockDim.x + threadIdx.x; e < TOTAL; e += stride) {
        float z0 = z[(size_t)e * 3];
        u32 b = bucket_of(z0);
        u32 r = (u32)e >> LOG_NPTS;
        u32 i = (u32)e & (NPTS - 1);
        u32 pos = atomicAdd(&cursors[(r << LOG_NBUCK) + b], 1u);
        recIdx[((size_t)r << LOG_NPTS) + pos] = i;
    }
}

__global__ __launch_bounds__(256) void bucket_sort_kernel(
        const float* __restrict__ z,
        const u32* __restrict__ offsets,
        const u32* __restrict__ cursors,
        const u32* __restrict__ recIdx,
        int* __restrict__ out_pa,
        int* __restrict__ out_re) {
    __shared__ u64 hi[4][CAP];
    __shared__ u64 lo[4][CAP];
    __shared__ u32 cnts[4];
    int w = threadIdx.x >> 6;
    int lane = threadIdx.x & 63;
    int g = blockIdx.x * 4 + w;                 // global bucket id
    int r = g >> LOG_NBUCK;
    u32 start = offsets[g];
    u32 end   = cursors[g];
    u32 count = end - start;
    if (count > CAP) count = CAP;               // P(overflow) ~ 1e-40; guard OOB
    const float* zr = z + ((size_t)r * NPTS) * 3;
    const u32* rec = recIdx + ((size_t)r << LOG_NPTS) + start;

    for (int t = lane; t < CAP; t += 64) {
        u64 h = ~0ull, l = ~0ull;
        if (t < (int)count) {
            u32 i = rec[t];
            const float* p = zr + (size_t)i * 3;
            u32 k0 = __float_as_uint(p[0]);
            u32 k1 = __float_as_uint(p[1]);
            u32 k2 = __float_as_uint(p[2]);
            h = ((u64)k0 << 32) | (u64)k1;
            l = ((u64)k2 << 32) | (u64)i;
        }
        hi[w][t] = h;
        lo[w][t] = l;
    }
    if (lane == 0) cnts[w] = count;
    __syncthreads();

    u32 m01 = cnts[0] > cnts[1] ? cnts[0] : cnts[1];
    u32 m23 = cnts[2] > cnts[3] ? cnts[2] : cnts[3];
    u32 m = m01 > m23 ? m01 : m23;
    u32 n = 2;
    while (n < m) n <<= 1;                      // network size (uniform in block)

    for (u32 k = 2; k <= n; k <<= 1) {
        for (u32 j = k >> 1; j > 0; j >>= 1) {
            u32 p = (u32)lane;                  // pair id
            if (p < (n >> 1)) {
                u32 i = ((p & ~(j - 1)) << 1) | (p & (j - 1));
                u32 x = i | j;
                u64 ahi = hi[w][i], alo = lo[w][i];
                u64 bhi = hi[w][x], blo = lo[w][x];
                bool agtb = (ahi != bhi) ? (ahi > bhi) : (alo > blo);
                bool up = ((i & k) == 0);
                if (agtb == up) {
                    hi[w][i] = bhi; lo[w][i] = blo;
                    hi[w][x] = ahi; lo[w][x] = alo;
                }
            }
            __syncthreads();
        }
    }

    for (int t = lane; t < (int)count; t += 64) {
        u32 si = (u32)(lo[w][t] & 0xFFFFFFFFu);
        u32 pos = start + (u32)t;
        out_pa[((size_t)r << LOG_NPTS) + pos] = (int)si;
        out_re[((size_t)r << LOG_NPTS) + si]  = (int)pos;
    }
}

extern "C" void kernel_launch(void* const* d_in, const int* in_sizes, int n_in,
                              void* d_out, int out_size, void* d_ws, size_t ws_size,
                              hipStream_t stream) {
    const float* z = (const float*)d_in[0];
    int* out_pa = (int*)d_out;
    int* out_re = out_pa + TOTAL;

    char* ws = (char*)d_ws;
    u32* counts  = (u32*)(ws);                       // 1 MB
    u32* offsets = (u32*)(ws + (1u << 20));          // 1 MB
    u32* cursors = (u32*)(ws + (2u << 20));          // 1 MB
    u32* recIdx  = (u32*)(ws + (3u << 20));          // 32 MB

    hipMemsetAsync(counts, 0, (size_t)BROWS * NBUCK * sizeof(u32), stream);
    hist_kernel<<<4096, 256, 0, stream>>>(z, counts);
    scan_kernel<<<BROWS, 256, 0, stream>>>(counts, offsets, cursors);
    scatter_kernel<<<4096, 256, 0, stream>>>(z, cursors, recIdx);
    bucket_sort_kernel<<<(BROWS * NBUCK) / 4, 256, 0, stream>>>(
        z, offsets, cursors, recIdx, out_pa, out_re);
}

// Round 2
// 458.349 us; speedup vs baseline: 2.5606x; 2.5606x over previous
//
#include <hip/hip_runtime.h>
#include <stdint.h>

typedef unsigned int u32;
typedef unsigned long long u64;
typedef unsigned char u8;

#define BROWS 32
#define NPTS  262144           // 2^18 per row
#define LOG_NPTS 18
#define CB 256                 // coarse buckets per row (top 8 bits of z0)
#define CHUNK 4096             // elements per multisplit workgroup
#define WGMS 1024              // multisplit workgroup size (4 elems/thread)
#define CCAP 1536              // LDS capacity per coarse bucket (mean 1024, 16 sigma)
#define FCAP 128               // fine bucket sort-network cap (mean 32)

// z0 in [0,1). *256 and *8192 are exact (power-of-2 scale), so
// fb_global>>5 == cb exactly — coarse/fine binning is consistent.
__device__ __forceinline__ u32 cb_of(float z0) {
    int b = (int)(z0 * 256.0f);
    return (u32)(b < 0 ? 0 : (b > 255 ? 255 : b));
}
__device__ __forceinline__ u32 fb_of(float z0) {
    int b = (int)(z0 * 8192.0f);
    b = b < 0 ? 0 : (b > 8191 ? 8191 : b);
    return (u32)b & 31u;
}

// ---------- pass 1: coarse histogram (LDS-aggregated) ----------
__global__ __launch_bounds__(256) void hist_kernel(const float* __restrict__ z,
                                                   u32* __restrict__ counts) {
    __shared__ u32 h[CB];
    for (int i = threadIdx.x; i < CB; i += 256) h[i] = 0;
    __syncthreads();
    int r = blockIdx.x >> 6;           // 64 chunks per row
    int c = blockIdx.x & 63;
    size_t base = ((size_t)r << LOG_NPTS) + (size_t)c * CHUNK;
    for (int k = 0; k < CHUNK / 256; ++k) {
        float z0 = z[(base + (size_t)(k * 256 + threadIdx.x)) * 3];
        atomicAdd(&h[cb_of(z0)], 1u);
    }
    __syncthreads();
    for (int i = threadIdx.x; i < CB; i += 256)
        if (h[i]) atomicAdd(&counts[r * CB + i], h[i]);
}

// ---------- pass 2: per-row exclusive scan of 256 coarse counts ----------
__global__ __launch_bounds__(256) void scan_kernel(const u32* __restrict__ counts,
                                                   u32* __restrict__ offsets,
                                                   u32* __restrict__ gcur) {
    int r = blockIdx.x, t = threadIdx.x;
    __shared__ u32 sc[CB];
    u32 v = counts[r * CB + t];
    sc[t] = v;
    __syncthreads();
    u32 own = v;
    for (int off = 1; off < CB; off <<= 1) {
        u32 a = (t >= off) ? sc[t - off] : 0;
        __syncthreads();
        sc[t] += a;
        __syncthreads();
    }
    u32 ex = sc[t] - own;
    offsets[r * CB + t] = ex;
    gcur[r * CB + t] = ex;
}

// ---------- pass 3: multisplit scatter of indices (line-friendly flush) ----------
__global__ __launch_bounds__(WGMS) void ms_scatter(const float* __restrict__ z,
                                                   u32* __restrict__ gcur,
                                                   u32* __restrict__ recIdx) {
    __shared__ u32 h[CB], sc[CB], gb[CB], lc[CB];
    __shared__ u32 reord[CHUNK];
    int t = threadIdx.x;
    int r = blockIdx.x >> 6;
    int c = blockIdx.x & 63;
    if (t < CB) h[t] = 0;
    __syncthreads();
    u32 mb[4], mi[4];
    size_t zbase = (((size_t)r << LOG_NPTS) + (size_t)c * CHUNK) * 3;
    for (int k = 0; k < 4; ++k) {
        u32 i = (u32)(c * CHUNK + k * WGMS + t);
        float z0 = z[zbase + (size_t)(k * WGMS + t) * 3];
        u32 b = cb_of(z0);
        mb[k] = b; mi[k] = i;
        atomicAdd(&h[b], 1u);
    }
    __syncthreads();
    if (t < CB) sc[t] = h[t];
    __syncthreads();
    for (int off = 1; off < CB; off <<= 1) {
        u32 a = 0;
        if (t < CB && t >= off) a = sc[t - off];
        __syncthreads();
        if (t < CB) sc[t] += a;
        __syncthreads();
    }
    if (t < CB) {
        gb[t] = atomicAdd(&gcur[r * CB + t], h[t]);
        lc[t] = sc[t] - h[t];          // running cursor from exclusive prefix
    }
    __syncthreads();
    for (int k = 0; k < 4; ++k) {
        u32 p = atomicAdd(&lc[mb[k]], 1u);
        reord[p] = (mb[k] << 18) | mi[k];
    }
    __syncthreads();
    for (int k = 0; k < 4; ++k) {
        u32 s = (u32)(k * WGMS + t);
        u32 v = reord[s];
        u32 b = v >> 18, i = v & 0x3FFFFu;
        u32 local = s - (sc[b] - h[b]);
        recIdx[((size_t)r << LOG_NPTS) + gb[b] + local] = i;
    }
}

// ---------- pass 4: per-coarse-bucket fine sort, write out_pa ----------
__global__ __launch_bounds__(256) void fine_sort(const float* __restrict__ z,
                                                 const u32* __restrict__ offsets,
                                                 const u32* __restrict__ recIdx,
                                                 int* __restrict__ out_pa) {
    __shared__ u64 khi[CCAP], klo[CCAP];
    __shared__ u32 fh[32], fex[32], fcur[32];
    __shared__ u64 sh[4][FCAP], sl[4][FCAP];
    int t = threadIdx.x;
    int g = blockIdx.x;
    int r = g >> 8, cbk = g & 255;
    u32 start = offsets[g];
    u32 end = (cbk == 255) ? (u32)NPTS : offsets[g + 1];
    u32 count = end - start;
    if (count > CCAP) count = CCAP;    // P ~ 0
    if (t < 32) { fh[t] = 0; fcur[t] = 0; }
    __syncthreads();

    u64 rh[6], rl[6];
    u32 rb[6];
    int nk = 0;
    for (u32 s = t; s < count; s += 256) {
        u32 i = recIdx[((size_t)r << LOG_NPTS) + start + s];
        const float* p = z + (((size_t)r << LOG_NPTS) + i) * 3;
        float f0 = p[0], f1 = p[1], f2 = p[2];
        u32 k0 = __float_as_uint(f0), k1 = __float_as_uint(f1), k2 = __float_as_uint(f2);
        rh[nk] = ((u64)k0 << 32) | k1;
        rl[nk] = ((u64)k2 << 32) | i;
        u32 fb = fb_of(f0);
        rb[nk] = fb;
        ++nk;
        atomicAdd(&fh[fb], 1u);
    }
    __syncthreads();
    if (t == 0) {
        u32 acc = 0;
        for (int q = 0; q < 32; ++q) { fex[q] = acc; acc += fh[q]; }
    }
    __syncthreads();
    int kk = 0;
    for (u32 s = t; s < count; s += 256) {
        u32 p = fex[rb[kk]] + atomicAdd(&fcur[rb[kk]], 1u);
        khi[p] = rh[kk];
        klo[p] = rl[kk];
        ++kk;
    }
    __syncthreads();

    // per-wave independent bitonic over 8 fine buckets each
    int w = t >> 6, lane = t & 63;
    for (int q = 0; q < 8; ++q) {
        u32 fb = (u32)(w * 8 + q);
        u32 cnt = fh[fb];
        if (cnt > FCAP) cnt = FCAP;    // P ~ 0
        u32 base = fex[fb];
        u32 n = 2;
        while (n < cnt) n <<= 1;
        for (u32 j = lane; j < n; j += 64) {
            u64 hh = ~0ull, ll = ~0ull;
            if (j < cnt) { hh = khi[base + j]; ll = klo[base + j]; }
            sh[w][j] = hh; sl[w][j] = ll;
        }
        __builtin_amdgcn_wave_barrier();
        for (u32 k = 2; k <= n; k <<= 1) {
            for (u32 jj = k >> 1; jj > 0; jj >>= 1) {
                u32 pp = (u32)lane;
                if (pp < (n >> 1)) {
                    u32 i2 = ((pp & ~(jj - 1)) << 1) | (pp & (jj - 1));
                    u32 x2 = i2 | jj;
                    u64 ah = sh[w][i2], al = sl[w][i2];
                    u64 bh = sh[w][x2], bl = sl[w][x2];
                    bool agtb = (ah != bh) ? (ah > bh) : (al > bl);
                    if (agtb == ((i2 & k) == 0)) {
                        sh[w][i2] = bh; sl[w][i2] = bl;
                        sh[w][x2] = ah; sl[w][x2] = al;
                    }
                }
                __builtin_amdgcn_wave_barrier();
            }
        }
        for (u32 j = lane; j < cnt; j += 64)
            out_pa[((size_t)r << LOG_NPTS) + start + base + j] =
                (int)(u32)(sl[w][j] & 0x3FFFFu);
    }
}

// ---------- pass 5: multisplit-transpose of the permutation ----------
__global__ __launch_bounds__(WGMS) void trans_ms(const int* __restrict__ out_pa,
                                                 u32* __restrict__ tcur,
                                                 u32* __restrict__ pairs) {
    __shared__ u32 h[CB], sc[CB], gb[CB], lc[CB];
    __shared__ u32 reord[CHUNK];
    __shared__ u8 rb8[CHUNK];
    int t = threadIdx.x;
    int r = blockIdx.x >> 6;
    int c = blockIdx.x & 63;
    if (t < CB) h[t] = 0;
    __syncthreads();
    u32 mb[4], mv[4];
    for (int k = 0; k < 4; ++k) {
        u32 p = (u32)(c * CHUNK + k * WGMS + t);         // position within row
        u32 si = (u32)out_pa[((size_t)r << LOG_NPTS) + p];
        u32 b = si >> 10;                                 // 256 buckets of exactly 1024
        mb[k] = b;
        mv[k] = ((si & 1023u) << 18) | p;
        atomicAdd(&h[b], 1u);
    }
    __syncthreads();
    if (t < CB) sc[t] = h[t];
    __syncthreads();
    for (int off = 1; off < CB; off <<= 1) {
        u32 a = 0;
        if (t < CB && t >= off) a = sc[t - off];
        __syncthreads();
        if (t < CB) sc[t] += a;
        __syncthreads();
    }
    if (t < CB) {
        gb[t] = atomicAdd(&tcur[r * CB + t], h[t]);
        lc[t] = sc[t] - h[t];
    }
    __syncthreads();
    for (int k = 0; k < 4; ++k) {
        u32 p = atomicAdd(&lc[mb[k]], 1u);
        reord[p] = mv[k];
        rb8[p] = (u8)mb[k];
    }
    __syncthreads();
    for (int k = 0; k < 4; ++k) {
        u32 s = (u32)(k * WGMS + t);
        u32 v = reord[s];
        u32 b = rb8[s];
        u32 local = s - (sc[b] - h[b]);
        pairs[((size_t)r << LOG_NPTS) + (size_t)b * 1024 + gb[b] + local] = v;
    }
}

// ---------- pass 6: per-bucket reorder, coalesced out_re write ----------
__global__ __launch_bounds__(256) void trans_write(const u32* __restrict__ pairs,
                                                   int* __restrict__ out_re) {
    __shared__ u32 buf[1024];
    int g = blockIdx.x;
    int r = g >> 8, b = g & 255;
    size_t base = ((size_t)r << LOG_NPTS) + (size_t)b * 1024;
    for (int k = 0; k < 4; ++k) {
        u32 v = pairs[base + (size_t)(k * 256 + threadIdx.x)];
        buf[v >> 18] = v & 0x3FFFFu;                      // buf[si_low] = pos
    }
    __syncthreads();
    for (int k = 0; k < 4; ++k) {
        int j = k * 256 + threadIdx.x;
        out_re[base + (size_t)j] = (int)buf[j];
    }
}

extern "C" void kernel_launch(void* const* d_in, const int* in_sizes, int n_in,
                              void* d_out, int out_size, void* d_ws, size_t ws_size,
                              hipStream_t stream) {
    const float* z = (const float*)d_in[0];
    int* out_pa = (int*)d_out;
    int* out_re = out_pa + (size_t)BROWS * NPTS;

    char* ws = (char*)d_ws;
    u32* counts  = (u32*)(ws);                 // 32 KB
    u32* offsets = (u32*)(ws + (64u << 10));   // 32 KB
    u32* gcur    = (u32*)(ws + (128u << 10));  // 32 KB
    u32* tcur    = (u32*)(ws + (192u << 10));  // 32 KB
    u32* recIdx  = (u32*)(ws + (1u << 20));    // 32 MB (reused as `pairs` after pass 4)
    u32* pairs   = recIdx;

    hipMemsetAsync(counts, 0, (size_t)BROWS * CB * sizeof(u32), stream);
    hipMemsetAsync(tcur, 0, (size_t)BROWS * CB * sizeof(u32), stream);

    hist_kernel<<<BROWS * 64, 256, 0, stream>>>(z, counts);
    scan_kernel<<<BROWS, 256, 0, stream>>>(counts, offsets, gcur);
    ms_scatter<<<BROWS * 64, WGMS, 0, stream>>>(z, gcur, recIdx);
    fine_sort<<<BROWS * CB, 256, 0, stream>>>(z, offsets, recIdx, out_pa);
    trans_ms<<<BROWS * 64, WGMS, 0, stream>>>(out_pa, tcur, pairs);
    trans_write<<<BROWS * CB, 256, 0, stream>>>(pairs, out_re);
}

// Round 3
// 237.101 us; speedup vs baseline: 4.9500x; 1.9331x over previous
//
#include <hip/hip_runtime.h>
#include <stdint.h>

typedef unsigned int u32;
typedef unsigned long long u64;
typedef unsigned char u8;

#define BROWS 32
#define NPTS  262144           // 2^18 per row
#define LOG_NPTS 18
#define CB 256                 // coarse buckets per row (floor(z0*256))
#define CCAP 1536              // LDS staging cap per coarse bucket (mean 1024)
#define FPAD 96                // per-fine-bucket element cap (mean 32, P(>96)~4e-20)

// multisplit (records) geometry
#define MCH 2048
#define MWG 512
// transpose multisplit geometry
#define TCH 4096
#define TWG 1024

// z0 in [0,1). *256 / *8192 are exact pow2 scalings, so (int)(z0*8192)>>5 == (int)(z0*256).
__device__ __forceinline__ u32 cb_of(float z0) {
    int b = (int)(z0 * 256.0f);
    return (u32)(b < 0 ? 0 : (b > 255 ? 255 : b));
}
__device__ __forceinline__ u32 fb_of(float z0) {
    int b = (int)(z0 * 8192.0f);
    b = b < 0 ? 0 : (b > 8191 ? 8191 : b);
    return (u32)b & 31u;
}

// ---------- pass 1: coarse histogram ----------
__global__ __launch_bounds__(256) void hist_kernel(const float* __restrict__ z,
                                                   u32* __restrict__ counts) {
    __shared__ u32 h[CB];
    for (int i = threadIdx.x; i < CB; i += 256) h[i] = 0;
    __syncthreads();
    int r = blockIdx.x >> 6;           // 64 chunks of 4096 per row
    int c = blockIdx.x & 63;
    size_t base = ((size_t)r << LOG_NPTS) + (size_t)c * 4096;
    for (int k = 0; k < 16; ++k) {
        float z0 = z[(base + (size_t)(k * 256 + threadIdx.x)) * 3];
        atomicAdd(&h[cb_of(z0)], 1u);
    }
    __syncthreads();
    for (int i = threadIdx.x; i < CB; i += 256)
        if (h[i]) atomicAdd(&counts[r * CB + i], h[i]);
}

// ---------- pass 2: per-row exclusive scan ----------
__global__ __launch_bounds__(256) void scan_kernel(const u32* __restrict__ counts,
                                                   u32* __restrict__ offsets,
                                                   u32* __restrict__ gcur) {
    int r = blockIdx.x, t = threadIdx.x;
    __shared__ u32 sc[CB];
    u32 v = counts[r * CB + t];
    sc[t] = v;
    __syncthreads();
    u32 own = v;
    for (int off = 1; off < CB; off <<= 1) {
        u32 a = (t >= off) ? sc[t - off] : 0;
        __syncthreads();
        sc[t] += a;
        __syncthreads();
    }
    u32 ex = sc[t] - own;
    offsets[r * CB + t] = ex;
    gcur[r * CB + t] = ex;
}

// ---------- pass 3: multisplit scatter of FULL 16B records ----------
__global__ __launch_bounds__(MWG) void ms_scatter(const float* __restrict__ z,
                                                  u32* __restrict__ gcur,
                                                  u64* __restrict__ recHi,
                                                  u64* __restrict__ recLo) {
    __shared__ u32 h[CB], sc[CB], gb[CB], lc[CB];
    __shared__ u64 rHi[MCH], rLo[MCH];
    int t = threadIdx.x;
    int r = blockIdx.x >> 7;           // 128 chunks of 2048 per row
    int c = blockIdx.x & 127;
    if (t < CB) h[t] = 0;
    __syncthreads();
    u64 mh[4], ml[4];
    u32 mb[4];
    size_t zbase = (((size_t)r << LOG_NPTS) + (size_t)c * MCH) * 3;
#pragma unroll
    for (int k = 0; k < 4; ++k) {
        u32 i = (u32)(c * MCH + k * MWG + t);
        const float* p = z + zbase + (size_t)(k * MWG + t) * 3;
        float f0 = p[0], f1 = p[1], f2 = p[2];
        u32 k0 = __float_as_uint(f0), k1 = __float_as_uint(f1), k2 = __float_as_uint(f2);
        mh[k] = ((u64)k0 << 32) | k1;
        ml[k] = ((u64)k2 << 32) | i;
        u32 b = cb_of(f0);
        mb[k] = b;
        atomicAdd(&h[b], 1u);
    }
    __syncthreads();
    if (t < CB) sc[t] = h[t];
    __syncthreads();
    for (int off = 1; off < CB; off <<= 1) {
        u32 a = 0;
        if (t < CB && t >= off) a = sc[t - off];
        __syncthreads();
        if (t < CB) sc[t] += a;
        __syncthreads();
    }
    if (t < CB) {
        gb[t] = atomicAdd(&gcur[r * CB + t], h[t]);
        lc[t] = sc[t] - h[t];
    }
    __syncthreads();
#pragma unroll
    for (int k = 0; k < 4; ++k) {
        u32 p = atomicAdd(&lc[mb[k]], 1u);
        rHi[p] = mh[k];
        rLo[p] = ml[k];
    }
    __syncthreads();
    size_t rowrec = (size_t)r << LOG_NPTS;
#pragma unroll
    for (int k = 0; k < 4; ++k) {
        u32 s = (u32)(k * MWG + t);
        u64 vh = rHi[s];
        u32 b = cb_of(__uint_as_float((u32)(vh >> 32)));
        u32 local = s - (sc[b] - h[b]);
        size_t dest = rowrec + gb[b] + local;
        recHi[dest] = vh;
        recLo[dest] = rLo[s];
    }
}

// ---------- pass 4: per-coarse-bucket rank sort, write out_pa ----------
__global__ __launch_bounds__(256) void fine_sort(const u64* __restrict__ recHi,
                                                 const u64* __restrict__ recLo,
                                                 const u32* __restrict__ offsets,
                                                 int* __restrict__ out_pa) {
    __shared__ u64 kv[(CCAP + FPAD) * 2];     // interleaved (hi,lo), 16B/elem
    __shared__ u32 fh[32], fex[32], fcur[32];
    int t = threadIdx.x;
    int g = blockIdx.x;
    int r = g >> 8;
    int cbk = g & 255;
    size_t rowrec = (size_t)r << LOG_NPTS;
    u32 start = offsets[g];
    u32 end = (cbk == 255) ? (u32)NPTS : offsets[g + 1];
    u32 count = end - start;
    if (count > CCAP) count = CCAP;           // P ~ 0
    if (t < 32) { fh[t] = 0; fcur[t] = 0; }
    __syncthreads();

    u64 rh[6], rl[6];
    u32 rb[6];
#pragma unroll
    for (int k = 0; k < 6; ++k) {
        u32 s = (u32)t + (u32)k * 256u;
        rb[k] = 0xFFFFFFFFu;
        if (s < count) {
            u64 hi = recHi[rowrec + start + s];
            u64 lo = recLo[rowrec + start + s];
            rh[k] = hi; rl[k] = lo;
            u32 fb = fb_of(__uint_as_float((u32)(hi >> 32)));
            rb[k] = fb;
            atomicAdd(&fh[fb], 1u);
        }
    }
    __syncthreads();
    if (t == 0) {
        u32 acc = 0;
        for (int q = 0; q < 32; ++q) { fex[q] = acc; acc += fh[q]; }
    }
    __syncthreads();
#pragma unroll
    for (int k = 0; k < 6; ++k) {
        if (rb[k] != 0xFFFFFFFFu) {
            u32 p = fex[rb[k]] + atomicAdd(&fcur[rb[k]], 1u);
            kv[2 * p] = rh[k];
            kv[2 * p + 1] = rl[k];
        }
    }
    __syncthreads();

    // rank phase: each wave handles a PAIR of fine buckets (32 lanes each)
    int w = t >> 6, lane = t & 63;
    int half = lane >> 5, li = lane & 31;
    size_t orow = (size_t)r << LOG_NPTS;
    for (int pr = w; pr < 16; pr += 4) {
        u32 fbA = (u32)(pr * 2), fbB = fbA + 1;
        u32 cntA = fh[fbA]; if (cntA > FPAD) cntA = FPAD;
        u32 cntB = fh[fbB]; if (cntB > FPAD) cntB = FPAD;
        u32 myc = half ? cntB : cntA;
        u32 base = half ? fex[fbB] : fex[fbA];
        u32 mx = cntA > cntB ? cntA : cntB;

        u64 eh0 = 0, el0 = 0, eh1 = 0, el1 = 0, eh2 = 0, el2 = 0;
        bool v0 = (u32)li < myc;
        bool v1 = (u32)li + 32u < myc;
        bool v2 = (u32)li + 64u < myc;
        if (v0) { eh0 = kv[2 * (base + li)];      el0 = kv[2 * (base + li) + 1]; }
        if (v1) { eh1 = kv[2 * (base + li + 32)]; el1 = kv[2 * (base + li + 32) + 1]; }
        if (v2) { eh2 = kv[2 * (base + li + 64)]; el2 = kv[2 * (base + li + 64) + 1]; }
        u32 r0 = 0, r1 = 0, r2 = 0;

        if (mx > 64) {                 // rare slow path: 3 elements/lane
            for (u32 j = 0; j < mx; ++j) {
                u64 bh = kv[2 * (base + j)], bl = kv[2 * (base + j) + 1];
                bool in = j < myc;
                if (in && v0) r0 += (bh < eh0) || (bh == eh0 && bl < el0);
                if (in && v1) r1 += (bh < eh1) || (bh == eh1 && bl < el1);
                if (in && v2) r2 += (bh < eh2) || (bh == eh2 && bl < el2);
            }
        } else if (mx > 32) {          // 2 elements/lane
            for (u32 j = 0; j < mx; ++j) {
                u64 bh = kv[2 * (base + j)], bl = kv[2 * (base + j) + 1];
                bool in = j < myc;
                if (in && v0) r0 += (bh < eh0) || (bh == eh0 && bl < el0);
                if (in && v1) r1 += (bh < eh1) || (bh == eh1 && bl < el1);
            }
        } else {                       // common path: 1 element/lane
            for (u32 j = 0; j < mx; ++j) {
                u64 bh = kv[2 * (base + j)], bl = kv[2 * (base + j) + 1];
                if (j < myc && v0) r0 += (bh < eh0) || (bh == eh0 && bl < el0);
            }
        }
        if (v0) out_pa[orow + start + base + r0] = (int)(u32)(el0 & 0x3FFFFu);
        if (v1) out_pa[orow + start + base + r1] = (int)(u32)(el1 & 0x3FFFFu);
        if (v2) out_pa[orow + start + base + r2] = (int)(u32)(el2 & 0x3FFFFu);
    }
}

// ---------- pass 5: multisplit-transpose of the permutation ----------
__global__ __launch_bounds__(TWG) void trans_ms(const int* __restrict__ out_pa,
                                                u32* __restrict__ tcur,
                                                u32* __restrict__ pairs) {
    __shared__ u32 h[CB], sc[CB], gb[CB], lc[CB];
    __shared__ u32 reord[TCH];
    __shared__ u8 rb8[TCH];
    int t = threadIdx.x;
    int r = blockIdx.x >> 6;
    int c = blockIdx.x & 63;
    if (t < CB) h[t] = 0;
    __syncthreads();
    u32 mb[4], mv[4];
#pragma unroll
    for (int k = 0; k < 4; ++k) {
        u32 p = (u32)(c * TCH + k * TWG + t);
        u32 si = (u32)out_pa[((size_t)r << LOG_NPTS) + p];
        u32 b = si >> 10;
        mb[k] = b;
        mv[k] = ((si & 1023u) << 18) | p;
        atomicAdd(&h[b], 1u);
    }
    __syncthreads();
    if (t < CB) sc[t] = h[t];
    __syncthreads();
    for (int off = 1; off < CB; off <<= 1) {
        u32 a = 0;
        if (t < CB && t >= off) a = sc[t - off];
        __syncthreads();
        if (t < CB) sc[t] += a;
        __syncthreads();
    }
    if (t < CB) {
        gb[t] = atomicAdd(&tcur[r * CB + t], h[t]);
        lc[t] = sc[t] - h[t];
    }
    __syncthreads();
#pragma unroll
    for (int k = 0; k < 4; ++k) {
        u32 p = atomicAdd(&lc[mb[k]], 1u);
        reord[p] = mv[k];
        rb8[p] = (u8)mb[k];
    }
    __syncthreads();
#pragma unroll
    for (int k = 0; k < 4; ++k) {
        u32 s = (u32)(k * TWG + t);
        u32 v = reord[s];
        u32 b = rb8[s];
        u32 local = s - (sc[b] - h[b]);
        pairs[((size_t)r << LOG_NPTS) + (size_t)b * 1024 + gb[b] + local] = v;
    }
}

// ---------- pass 6: per-bucket reorder, coalesced out_re write ----------
__global__ __launch_bounds__(256) void trans_write(const u32* __restrict__ pairs,
                                                   int* __restrict__ out_re) {
    __shared__ u32 buf[1024];
    int g = blockIdx.x;
    int r = g >> 8, b = g & 255;
    size_t base = ((size_t)r << LOG_NPTS) + (size_t)b * 1024;
#pragma unroll
    for (int k = 0; k < 4; ++k) {
        u32 v = pairs[base + (size_t)(k * 256 + threadIdx.x)];
        buf[v >> 18] = v & 0x3FFFFu;
    }
    __syncthreads();
#pragma unroll
    for (int k = 0; k < 4; ++k) {
        int j = k * 256 + threadIdx.x;
        out_re[base + (size_t)j] = (int)buf[j];
    }
}

extern "C" void kernel_launch(void* const* d_in, const int* in_sizes, int n_in,
                              void* d_out, int out_size, void* d_ws, size_t ws_size,
                              hipStream_t stream) {
    const float* z = (const float*)d_in[0];
    int* out_pa = (int*)d_out;
    int* out_re = out_pa + (size_t)BROWS * NPTS;

    char* ws = (char*)d_ws;
    u32* counts  = (u32*)(ws);                 // 32 KB
    u32* offsets = (u32*)(ws + (64u << 10));   // 32 KB
    u32* gcur    = (u32*)(ws + (128u << 10));  // 32 KB
    u32* tcur    = (u32*)(ws + (192u << 10));  // 32 KB
    u64* recHi   = (u64*)(ws + (1u << 20));            // 64 MB
    u64* recLo   = (u64*)(ws + (1u << 20) + (64u << 20)); // 64 MB
    u32* pairs   = (u32*)recHi;                // 32 MB, reused after pass 4

    hipMemsetAsync(counts, 0, (size_t)BROWS * CB * sizeof(u32), stream);
    hipMemsetAsync(tcur, 0, (size_t)BROWS * CB * sizeof(u32), stream);

    hist_kernel<<<BROWS * 64, 256, 0, stream>>>(z, counts);
    scan_kernel<<<BROWS, 256, 0, stream>>>(counts, offsets, gcur);
    ms_scatter<<<BROWS * 128, MWG, 0, stream>>>(z, gcur, recHi, recLo);
    fine_sort<<<BROWS * CB, 256, 0, stream>>>(recHi, recLo, offsets, out_pa);
    trans_ms<<<BROWS * 64, TWG, 0, stream>>>(out_pa, tcur, pairs);
    trans_write<<<BROWS * CB, 256, 0, stream>>>(pairs, out_re);
}

// Round 4
// 196.486 us; speedup vs baseline: 5.9732x; 1.2067x over previous
//
#include <hip/hip_runtime.h>
#include <stdint.h>

typedef unsigned int u32;
typedef unsigned long long u64;
typedef unsigned char u8;

#define BROWS 32
#define NPTS  262144           // 2^18 per row
#define LOG_NPTS 18
#define CB 256                 // coarse buckets per row (floor(z0*256))
#define CCAP 1536              // LDS staging cap per coarse bucket (mean 1024, 16 sigma)
#define FB 64                  // fine buckets per coarse bucket (mean 16)
#define FPAD 64                // per-fine-bucket cap (P(Po(16)>64) ~ 1e-21)

// multisplit geometry
#define MCH 4096
#define MWG 512
// transpose multisplit geometry
#define TCH 4096
#define TWG 1024

// z0 in [0,1). *256 / *16384 are exact pow2 scalings; floor(z0*16384)>>6 == floor(z0*256).
__device__ __forceinline__ u32 cb_of(float z0) {
    int b = (int)(z0 * 256.0f);
    return (u32)(b < 0 ? 0 : (b > 255 ? 255 : b));
}
__device__ __forceinline__ u32 fb_of(float z0) {
    int b = (int)(z0 * 16384.0f);
    b = b < 0 ? 0 : (b > 16383 ? 16383 : b);
    return (u32)b & (FB - 1);
}

// ---------- pass 1: coarse histogram ----------
__global__ __launch_bounds__(256) void hist_kernel(const float* __restrict__ z,
                                                   u32* __restrict__ counts) {
    __shared__ u32 h[CB];
    for (int i = threadIdx.x; i < CB; i += 256) h[i] = 0;
    __syncthreads();
    int r = blockIdx.x >> 6;
    int c = blockIdx.x & 63;
    size_t base = ((size_t)r << LOG_NPTS) + (size_t)c * 4096;
    for (int k = 0; k < 16; ++k) {
        float z0 = z[(base + (size_t)(k * 256 + threadIdx.x)) * 3];
        atomicAdd(&h[cb_of(z0)], 1u);
    }
    __syncthreads();
    for (int i = threadIdx.x; i < CB; i += 256)
        if (h[i]) atomicAdd(&counts[r * CB + i], h[i]);
}

// ---------- pass 2: per-row exclusive scan ----------
__global__ __launch_bounds__(256) void scan_kernel(const u32* __restrict__ counts,
                                                   u32* __restrict__ offsets,
                                                   u32* __restrict__ gcur) {
    int r = blockIdx.x, t = threadIdx.x;
    __shared__ u32 sc[CB];
    u32 v = counts[r * CB + t];
    sc[t] = v;
    __syncthreads();
    u32 own = v;
    for (int off = 1; off < CB; off <<= 1) {
        u32 a = (t >= off) ? sc[t - off] : 0;
        __syncthreads();
        sc[t] += a;
        __syncthreads();
    }
    u32 ex = sc[t] - own;
    offsets[r * CB + t] = ex;
    gcur[r * CB + t] = ex;
}

// ---------- pass 3: multisplit scatter of 16B records (interleaved hi,lo) ----------
__global__ __launch_bounds__(MWG) void ms_scatter(const float* __restrict__ z,
                                                  u32* __restrict__ gcur,
                                                  u64* __restrict__ recKV) {
    __shared__ u32 h[CB], sc[CB], gb[CB];
    __shared__ u64 rKV[MCH * 2];
    int t = threadIdx.x;
    int r = blockIdx.x >> 6;           // 64 chunks of 4096 per row
    int c = blockIdx.x & 63;
    if (t < CB) h[t] = 0;
    __syncthreads();
    u64 mh[8], ml[8];
    u32 mpk[8];                         // (bucket<<16) | arrival
    size_t zbase = (((size_t)r << LOG_NPTS) + (size_t)c * MCH) * 3;
#pragma unroll
    for (int k = 0; k < 8; ++k) {
        u32 i = (u32)(c * MCH + k * MWG + t);
        const float* p = z + zbase + (size_t)(k * MWG + t) * 3;
        float f0 = p[0], f1 = p[1], f2 = p[2];
        u32 k0 = __float_as_uint(f0), k1 = __float_as_uint(f1), k2 = __float_as_uint(f2);
        mh[k] = ((u64)k0 << 32) | k1;
        ml[k] = ((u64)k2 << 32) | i;
        u32 b = cb_of(f0);
        u32 arr = atomicAdd(&h[b], 1u);
        mpk[k] = (b << 16) | arr;
    }
    __syncthreads();
    if (t < CB) sc[t] = h[t];
    __syncthreads();
    for (int off = 1; off < CB; off <<= 1) {
        u32 a = 0;
        if (t < CB && t >= off) a = sc[t - off];
        __syncthreads();
        if (t < CB) sc[t] += a;
        __syncthreads();
    }
    if (t < CB) {
        sc[t] -= h[t];                  // now exclusive prefix (LDS start)
        gb[t] = atomicAdd(&gcur[r * CB + t], h[t]);
    }
    __syncthreads();
#pragma unroll
    for (int k = 0; k < 8; ++k) {
        u32 b = mpk[k] >> 16, arr = mpk[k] & 0xFFFFu;
        u32 p = sc[b] + arr;
        rKV[2 * p] = mh[k];
        rKV[2 * p + 1] = ml[k];
    }
    __syncthreads();
    size_t rowrec = (size_t)r << LOG_NPTS;
#pragma unroll
    for (int k = 0; k < 8; ++k) {
        u32 s = (u32)(k * MWG + t);
        u64 vh = rKV[2 * s];
        u64 vl = rKV[2 * s + 1];
        u32 b = cb_of(__uint_as_float((u32)(vh >> 32)));
        u32 local = s - sc[b];
        size_t dest = rowrec + gb[b] + local;
        recKV[2 * dest] = vh;
        recKV[2 * dest + 1] = vl;
    }
}

// ---------- pass 4: per-coarse-bucket rank sort (64 fine buckets, quads) ----------
__global__ __launch_bounds__(256) void fine_sort(const u64* __restrict__ recKV,
                                                 const u32* __restrict__ offsets,
                                                 int* __restrict__ out_pa) {
    __shared__ u64 kv[(CCAP + FPAD) * 2];
    __shared__ u32 fh[FB], fex[FB];
    int t = threadIdx.x;
    int g = blockIdx.x;
    int r = g >> 8;
    int cbk = g & 255;
    size_t rowrec = (size_t)r << LOG_NPTS;
    u32 start = offsets[g];
    u32 end = (cbk == 255) ? (u32)NPTS : offsets[g + 1];
    u32 count = end - start;
    if (count > CCAP) count = CCAP;
    if (t < FB) fh[t] = 0;
    __syncthreads();

    u64 rh[6], rl[6];
    u32 rpk[6];
#pragma unroll
    for (int k = 0; k < 6; ++k) {
        u32 s = (u32)t + (u32)k * 256u;
        rpk[k] = 0xFFFFFFFFu;
        if (s < count) {
            u64 hi = recKV[2 * (rowrec + start + s)];
            u64 lo = recKV[2 * (rowrec + start + s) + 1];
            rh[k] = hi; rl[k] = lo;
            u32 fb = fb_of(__uint_as_float((u32)(hi >> 32)));
            u32 arr = atomicAdd(&fh[fb], 1u);
            rpk[k] = (fb << 16) | arr;
        }
    }
    __syncthreads();
    if (t < 64) {                       // wave-0 shfl scan of 64 counts
        u32 v = fh[t];
        u32 s = v;
        for (int off = 1; off < 64; off <<= 1) {
            u32 o = __shfl_up(s, off, 64);
            if ((t & 63) >= off) s += o;
        }
        fex[t] = s - v;
    }
    __syncthreads();
#pragma unroll
    for (int k = 0; k < 6; ++k) {
        if (rpk[k] != 0xFFFFFFFFu) {
            u32 fb = rpk[k] >> 16, arr = rpk[k] & 0xFFFFu;
            u32 p = fex[fb] + arr;
            if (p < CCAP + FPAD) {
                kv[2 * p] = rh[k];
                kv[2 * p + 1] = rl[k];
            }
        }
    }
    __syncthreads();

    // rank phase: each wave handles a QUAD of fine buckets (16 lanes each)
    int w = t >> 6, lane = t & 63;
    int q = lane >> 4, li = lane & 15;
    size_t orow = (size_t)r << LOG_NPTS;
    for (int qt = w; qt < 16; qt += 4) {
        u32 fb0 = (u32)(qt * 4);
        u32 c0 = fh[fb0];     c0 = c0 > FPAD ? FPAD : c0;
        u32 c1 = fh[fb0 + 1]; c1 = c1 > FPAD ? FPAD : c1;
        u32 c2 = fh[fb0 + 2]; c2 = c2 > FPAD ? FPAD : c2;
        u32 c3 = fh[fb0 + 3]; c3 = c3 > FPAD ? FPAD : c3;
        u32 m01 = c0 > c1 ? c0 : c1;
        u32 m23 = c2 > c3 ? c2 : c3;
        u32 mx = m01 > m23 ? m01 : m23;          // wave-uniform
        u32 myc = (q & 1) ? ((q & 2) ? c3 : c1) : ((q & 2) ? c2 : c0);
        u32 base = fex[fb0 + q];

        u64 eh0 = 0, el0 = 0, eh1 = 0, el1 = 0, eh2 = 0, el2 = 0, eh3 = 0, el3 = 0;
        bool v0 = (u32)li < myc;
        bool v1 = (u32)li + 16u < myc;
        bool v2 = (u32)li + 32u < myc;
        bool v3 = (u32)li + 48u < myc;
        if (v0) { eh0 = kv[2 * (base + li)];      el0 = kv[2 * (base + li) + 1]; }
        if (v1) { eh1 = kv[2 * (base + li + 16)]; el1 = kv[2 * (base + li + 16) + 1]; }
        if (v2) { eh2 = kv[2 * (base + li + 32)]; el2 = kv[2 * (base + li + 32) + 1]; }
        if (v3) { eh3 = kv[2 * (base + li + 48)]; el3 = kv[2 * (base + li + 48) + 1]; }
        u32 r0 = 0, r1 = 0, r2 = 0, r3 = 0;

        if (mx <= 16) {
            for (u32 j = 0; j < mx; ++j) {
                u64 bh = kv[2 * (base + j)], bl = kv[2 * (base + j) + 1];
                bool in = j < myc;
                if (in && v0) r0 += (bh < eh0) || (bh == eh0 && bl < el0);
            }
        } else if (mx <= 32) {
            for (u32 j = 0; j < mx; ++j) {
                u64 bh = kv[2 * (base + j)], bl = kv[2 * (base + j) + 1];
                bool in = j < myc;
                if (in && v0) r0 += (bh < eh0) || (bh == eh0 && bl < el0);
                if (in && v1) r1 += (bh < eh1) || (bh == eh1 && bl < el1);
            }
        } else if (mx <= 48) {
            for (u32 j = 0; j < mx; ++j) {
                u64 bh = kv[2 * (base + j)], bl = kv[2 * (base + j) + 1];
                bool in = j < myc;
                if (in && v0) r0 += (bh < eh0) || (bh == eh0 && bl < el0);
                if (in && v1) r1 += (bh < eh1) || (bh == eh1 && bl < el1);
                if (in && v2) r2 += (bh < eh2) || (bh == eh2 && bl < el2);
            }
        } else {
            for (u32 j = 0; j < mx; ++j) {
                u64 bh = kv[2 * (base + j)], bl = kv[2 * (base + j) + 1];
                bool in = j < myc;
                if (in && v0) r0 += (bh < eh0) || (bh == eh0 && bl < el0);
                if (in && v1) r1 += (bh < eh1) || (bh == eh1 && bl < el1);
                if (in && v2) r2 += (bh < eh2) || (bh == eh2 && bl < el2);
                if (in && v3) r3 += (bh < eh3) || (bh == eh3 && bl < el3);
            }
        }
        if (v0) out_pa[orow + start + base + r0] = (int)(u32)(el0 & 0x3FFFFu);
        if (v1) out_pa[orow + start + base + r1] = (int)(u32)(el1 & 0x3FFFFu);
        if (v2) out_pa[orow + start + base + r2] = (int)(u32)(el2 & 0x3FFFFu);
        if (v3) out_pa[orow + start + base + r3] = (int)(u32)(el3 & 0x3FFFFu);
    }
}

// ---------- pass 5: multisplit-transpose of the permutation ----------
__global__ __launch_bounds__(TWG) void trans_ms(const int* __restrict__ out_pa,
                                                u32* __restrict__ tcur,
                                                u32* __restrict__ pairs) {
    __shared__ u32 h[CB], sc[CB], gb[CB];
    __shared__ u32 reord[TCH];
    __shared__ u8 rb8[TCH];
    int t = threadIdx.x;
    int r = blockIdx.x >> 6;
    int c = blockIdx.x & 63;
    if (t < CB) h[t] = 0;
    __syncthreads();
    u32 mpk[4], mv[4];
#pragma unroll
    for (int k = 0; k < 4; ++k) {
        u32 p = (u32)(c * TCH + k * TWG + t);
        u32 si = (u32)out_pa[((size_t)r << LOG_NPTS) + p];
        u32 b = si >> 10;
        mv[k] = ((si & 1023u) << 18) | p;
        u32 arr = atomicAdd(&h[b], 1u);
        mpk[k] = (b << 16) | arr;
    }
    __syncthreads();
    if (t < CB) sc[t] = h[t];
    __syncthreads();
    for (int off = 1; off < CB; off <<= 1) {
        u32 a = 0;
        if (t < CB && t >= off) a = sc[t - off];
        __syncthreads();
        if (t < CB) sc[t] += a;
        __syncthreads();
    }
    if (t < CB) {
        sc[t] -= h[t];
        gb[t] = atomicAdd(&tcur[r * CB + t], h[t]);
    }
    __syncthreads();
#pragma unroll
    for (int k = 0; k < 4; ++k) {
        u32 b = mpk[k] >> 16, arr = mpk[k] & 0xFFFFu;
        u32 p = sc[b] + arr;
        reord[p] = mv[k];
        rb8[p] = (u8)b;
    }
    __syncthreads();
#pragma unroll
    for (int k = 0; k < 4; ++k) {
        u32 s = (u32)(k * TWG + t);
        u32 v = reord[s];
        u32 b = rb8[s];
        u32 local = s - sc[b];
        pairs[((size_t)r << LOG_NPTS) + (size_t)b * 1024 + gb[b] + local] = v;
    }
}

// ---------- pass 6: per-bucket reorder, coalesced out_re write ----------
__global__ __launch_bounds__(256) void trans_write(const u32* __restrict__ pairs,
                                                   int* __restrict__ out_re) {
    __shared__ u32 buf[1024];
    int g = blockIdx.x;
    int r = g >> 8, b = g & 255;
    size_t base = ((size_t)r << LOG_NPTS) + (size_t)b * 1024;
#pragma unroll
    for (int k = 0; k < 4; ++k) {
        u32 v = pairs[base + (size_t)(k * 256 + threadIdx.x)];
        buf[v >> 18] = v & 0x3FFFFu;
    }
    __syncthreads();
#pragma unroll
    for (int k = 0; k < 4; ++k) {
        int j = k * 256 + threadIdx.x;
        out_re[base + (size_t)j] = (int)buf[j];
    }
}

extern "C" void kernel_launch(void* const* d_in, const int* in_sizes, int n_in,
                              void* d_out, int out_size, void* d_ws, size_t ws_size,
                              hipStream_t stream) {
    const float* z = (const float*)d_in[0];
    int* out_pa = (int*)d_out;
    int* out_re = out_pa + (size_t)BROWS * NPTS;

    char* ws = (char*)d_ws;
    u32* counts  = (u32*)(ws);                 // 32 KB
    u32* offsets = (u32*)(ws + (64u << 10));   // 32 KB
    u32* gcur    = (u32*)(ws + (128u << 10));  // 32 KB
    u32* tcur    = (u32*)(ws + (192u << 10));  // 32 KB
    u64* recKV   = (u64*)(ws + (1u << 20));    // 128 MB interleaved (hi,lo)
    u32* pairs   = (u32*)recKV;                // 32 MB, reused after pass 4

    hipMemsetAsync(counts, 0, (size_t)BROWS * CB * sizeof(u32), stream);
    hipMemsetAsync(tcur, 0, (size_t)BROWS * CB * sizeof(u32), stream);

    hist_kernel<<<BROWS * 64, 256, 0, stream>>>(z, counts);
    scan_kernel<<<BROWS, 256, 0, stream>>>(counts, offsets, gcur);
    ms_scatter<<<BROWS * 64, MWG, 0, stream>>>(z, gcur, recKV);
    fine_sort<<<BROWS * CB, 256, 0, stream>>>(recKV, offsets, out_pa);
    trans_ms<<<BROWS * 64, TWG, 0, stream>>>(out_pa, tcur, pairs);
    trans_write<<<BROWS * CB, 256, 0, stream>>>(pairs, out_re);
}

// Round 5
// 162.598 us; speedup vs baseline: 7.2182x; 1.2084x over previous
//
#include <hip/hip_runtime.h>
#include <stdint.h>

typedef unsigned int u32;
typedef unsigned long long u64;
typedef unsigned char u8;

#define BROWS 32
#define NPTS  262144           // 2^18 per row
#define LOG_NPTS 18
#define CB 256                 // coarse buckets per row
#define RCAP 1280              // fixed-region capacity per coarse bucket (mean 1024, +8 sigma)
#define ROWSTRIDE_FIX (CB * RCAP)   // 327680 records per row (fixed mode)
#define CCAP 1536              // LDS staging cap per coarse bucket
#define FB2 1024               // fine buckets per coarse bucket (mean 1)

// multisplit geometry
#define MCH 4096
#define MWG 512
// transpose multisplit geometry
#define TCH 8192
#define TWG 1024

// exact 18-bit grid: z0*2^18 is an exact f32 scaling; cb = g18>>10, fb = g18&1023
__device__ __forceinline__ u32 g18_of(float z0) {
    int b = (int)(z0 * 262144.0f);
    return (u32)(b < 0 ? 0 : (b > 262143 ? 262143 : b));
}

// ---------- dense-mode pass 1: coarse histogram ----------
__global__ __launch_bounds__(256) void hist_kernel(const float* __restrict__ z,
                                                   u32* __restrict__ counts) {
    __shared__ u32 h[CB];
    for (int i = threadIdx.x; i < CB; i += 256) h[i] = 0;
    __syncthreads();
    int r = blockIdx.x >> 6;
    int c = blockIdx.x & 63;
    size_t base = ((size_t)r << LOG_NPTS) + (size_t)c * 4096;
    for (int k = 0; k < 16; ++k) {
        float z0 = z[(base + (size_t)(k * 256 + threadIdx.x)) * 3];
        atomicAdd(&h[g18_of(z0) >> 10], 1u);
    }
    __syncthreads();
    for (int i = threadIdx.x; i < CB; i += 256)
        if (h[i]) atomicAdd(&counts[r * CB + i], h[i]);
}

// ---------- dense-mode pass 2: scan counts -> offsets, gcur ----------
__global__ __launch_bounds__(256) void scan_dense(const u32* __restrict__ counts,
                                                  u32* __restrict__ offsets,
                                                  u32* __restrict__ gcur) {
    int r = blockIdx.x, t = threadIdx.x;
    __shared__ u32 sc[CB];
    u32 v = counts[r * CB + t];
    sc[t] = v;
    __syncthreads();
    u32 own = v;
    for (int off = 1; off < CB; off <<= 1) {
        u32 a = (t >= off) ? sc[t - off] : 0;
        __syncthreads();
        sc[t] += a;
        __syncthreads();
    }
    u32 ex = sc[t] - own;
    offsets[r * CB + t] = ex;
    gcur[r * CB + t] = ex;
}

// ---------- fixed-mode: init region cursors ----------
__global__ void init_fixed(u32* __restrict__ gcur) {
    int i = blockIdx.x * 256 + threadIdx.x;   // 8192 entries
    gcur[i] = (u32)(i & 255) * RCAP;
}

// ---------- fixed-mode: post-scatter scan (cursors -> counts, offsets) ----------
__global__ __launch_bounds__(256) void scan_fixed(const u32* __restrict__ gcur,
                                                  u32* __restrict__ offsets,
                                                  u32* __restrict__ counts) {
    int r = blockIdx.x, t = threadIdx.x;
    __shared__ u32 sc[CB];
    u32 cnt = gcur[r * CB + t] - (u32)t * RCAP;
    if (cnt > RCAP) cnt = RCAP;
    counts[r * CB + t] = cnt;
    sc[t] = cnt;
    __syncthreads();
    u32 own = cnt;
    for (int off = 1; off < CB; off <<= 1) {
        u32 a = (t >= off) ? sc[t - off] : 0;
        __syncthreads();
        sc[t] += a;
        __syncthreads();
    }
    offsets[r * CB + t] = sc[t] - own;
}

// ---------- pass 3: multisplit scatter of 16B records ----------
__global__ __launch_bounds__(MWG) void ms_scatter(const float* __restrict__ z,
                                                  u32* __restrict__ gcur,
                                                  ulonglong2* __restrict__ recKV,
                                                  int fixedMode) {
    __shared__ u32 h[CB], sc[CB], gb[CB];
    __shared__ ulonglong2 rKV[MCH];
    int t = threadIdx.x;
    int r = blockIdx.x >> 6;           // 64 chunks of 4096 per row
    int c = blockIdx.x & 63;
    if (t < CB) h[t] = 0;
    __syncthreads();
    u64 mh[8], ml[8];
    u32 mpk[8];                         // (bucket<<16) | arrival
    size_t zbase = (((size_t)r << LOG_NPTS) + (size_t)c * MCH) * 3;
#pragma unroll
    for (int k = 0; k < 8; ++k) {
        u32 i = (u32)(c * MCH + k * MWG + t);
        const float* p = z + zbase + (size_t)(k * MWG + t) * 3;
        float f0 = p[0], f1 = p[1], f2 = p[2];
        u32 k0 = __float_as_uint(f0), k1 = __float_as_uint(f1), k2 = __float_as_uint(f2);
        mh[k] = ((u64)k0 << 32) | k1;
        ml[k] = ((u64)k2 << 32) | i;
        u32 b = g18_of(f0) >> 10;
        u32 arr = atomicAdd(&h[b], 1u);
        mpk[k] = (b << 16) | arr;
    }
    __syncthreads();
    if (t < CB) sc[t] = h[t];
    __syncthreads();
    for (int off = 1; off < CB; off <<= 1) {
        u32 a = 0;
        if (t < CB && t >= off) a = sc[t - off];
        __syncthreads();
        if (t < CB) sc[t] += a;
        __syncthreads();
    }
    if (t < CB) {
        sc[t] -= h[t];                  // exclusive prefix (LDS start)
        gb[t] = atomicAdd(&gcur[r * CB + t], h[t]);
    }
    __syncthreads();
#pragma unroll
    for (int k = 0; k < 8; ++k) {
        u32 b = mpk[k] >> 16, arr = mpk[k] & 0xFFFFu;
        u32 p = sc[b] + arr;
        rKV[p].x = mh[k];
        rKV[p].y = ml[k];
    }
    __syncthreads();
    size_t rowrec = fixedMode ? (size_t)r * ROWSTRIDE_FIX : ((size_t)r << LOG_NPTS);
#pragma unroll
    for (int k = 0; k < 8; ++k) {
        u32 s = (u32)(k * MWG + t);
        ulonglong2 v = rKV[s];
        u32 b = g18_of(__uint_as_float((u32)(v.x >> 32))) >> 10;
        u32 local = s - sc[b];
        u32 dst = gb[b] + local;
        if (!fixedMode || dst < b * (u32)RCAP + (u32)RCAP)
            recKV[rowrec + dst] = v;
    }
}

// ---------- pass 4: per-coarse-bucket rank sort (1024 fine buckets, mean 1) ----------
__global__ __launch_bounds__(256) void fine_sort(const ulonglong2* __restrict__ recKV,
                                                 const u32* __restrict__ offsets,
                                                 const u32* __restrict__ counts,
                                                 int* __restrict__ out_pa,
                                                 int fixedMode) {
    __shared__ ulonglong2 kv2[CCAP];
    __shared__ u32 fh[FB2], fex[FB2], wtot[4];
    int t = threadIdx.x;
    int g = blockIdx.x;
    int r = g >> 8;
    int cbk = g & 255;
    size_t rowrec = fixedMode ? (size_t)r * ROWSTRIDE_FIX : ((size_t)r << LOG_NPTS);
    u32 rdstart = fixedMode ? (u32)cbk * RCAP : offsets[g];
    u32 wrstart = offsets[g];
    u32 count = counts[g];
    u32 cap = fixedMode ? (u32)RCAP : (u32)CCAP;
    if (count > cap) count = cap;
    for (int i = t; i < FB2; i += 256) fh[i] = 0;
    __syncthreads();

    u64 rh[6], rl[6];
    u32 rpk[6];
#pragma unroll
    for (int k = 0; k < 6; ++k) {
        u32 s = (u32)t + (u32)k * 256u;
        rpk[k] = 0xFFFFFFFFu;
        if (s < count) {
            ulonglong2 rec = recKV[rowrec + rdstart + s];
            rh[k] = rec.x; rl[k] = rec.y;
            u32 fb = g18_of(__uint_as_float((u32)(rec.x >> 32))) & (FB2 - 1);
            u32 arr = atomicAdd(&fh[fb], 1u);
            rpk[k] = (fb << 16) | arr;
        }
    }
    __syncthreads();
    // two-level scan of 1024 counts (4 per thread)
    {
        u32 v0 = fh[4 * t], v1 = fh[4 * t + 1], v2 = fh[4 * t + 2], v3 = fh[4 * t + 3];
        u32 tsum = v0 + v1 + v2 + v3;
        u32 s = tsum;
        int lane = t & 63, w = t >> 6;
        for (int off = 1; off < 64; off <<= 1) {
            u32 o = __shfl_up(s, off, 64);
            if (lane >= off) s += o;
        }
        if (lane == 63) wtot[w] = s;
        __syncthreads();
        u32 wbase = 0;
        if (w > 0) wbase += wtot[0];
        if (w > 1) wbase += wtot[1];
        if (w > 2) wbase += wtot[2];
        u32 ex = wbase + s - tsum;
        fex[4 * t] = ex;
        fex[4 * t + 1] = ex + v0;
        fex[4 * t + 2] = ex + v0 + v1;
        fex[4 * t + 3] = ex + v0 + v1 + v2;
    }
    __syncthreads();
#pragma unroll
    for (int k = 0; k < 6; ++k) {
        if (rpk[k] != 0xFFFFFFFFu) {
            u32 fb = rpk[k] >> 16, arr = rpk[k] & 0xFFFFu;
            u32 p = fex[fb] + arr;
            kv2[p].x = rh[k];
            kv2[p].y = rl[k];
        }
    }
    __syncthreads();

    size_t orow = (size_t)r << LOG_NPTS;
#pragma unroll
    for (int k = 0; k < 6; ++k) {
        if (rpk[k] == 0xFFFFFFFFu) continue;
        u32 fb = rpk[k] >> 16;
        u32 cnt = fh[fb];
        u32 rank = 0;
        if (cnt > 1) {
            u32 base = fex[fb];
            for (u32 j = 0; j < cnt; ++j) {
                ulonglong2 b2 = kv2[base + j];
                rank += (b2.x < rh[k]) || (b2.x == rh[k] && b2.y < rl[k]);
            }
        }
        u32 pos = fex[fb] + rank;
        out_pa[orow + wrstart + pos] = (int)(u32)(rl[k] & 0x3FFFFu);
    }
}

// ---------- pass 5: multisplit-transpose of the permutation ----------
__global__ __launch_bounds__(TWG) void trans_ms(const int* __restrict__ out_pa,
                                                u32* __restrict__ tcur,
                                                u32* __restrict__ pairs) {
    __shared__ u32 h[CB], sc[CB], gb[CB];
    __shared__ u32 reord[TCH];
    __shared__ u8 rb8[TCH];
    int t = threadIdx.x;
    int r = blockIdx.x >> 5;           // 32 chunks of 8192 per row
    int c = blockIdx.x & 31;
    if (t < CB) h[t] = 0;
    __syncthreads();
    u32 mpk[8], mv[8];
#pragma unroll
    for (int k = 0; k < 8; ++k) {
        u32 p = (u32)(c * TCH + k * TWG + t);
        u32 si = (u32)out_pa[((size_t)r << LOG_NPTS) + p];
        u32 b = si >> 10;
        mv[k] = ((si & 1023u) << 18) | p;
        u32 arr = atomicAdd(&h[b], 1u);
        mpk[k] = (b << 16) | arr;
    }
    __syncthreads();
    if (t < CB) sc[t] = h[t];
    __syncthreads();
    for (int off = 1; off < CB; off <<= 1) {
        u32 a = 0;
        if (t < CB && t >= off) a = sc[t - off];
        __syncthreads();
        if (t < CB) sc[t] += a;
        __syncthreads();
    }
    if (t < CB) {
        sc[t] -= h[t];
        gb[t] = atomicAdd(&tcur[r * CB + t], h[t]);
    }
    __syncthreads();
#pragma unroll
    for (int k = 0; k < 8; ++k) {
        u32 b = mpk[k] >> 16, arr = mpk[k] & 0xFFFFu;
        u32 p = sc[b] + arr;
        reord[p] = mv[k];
        rb8[p] = (u8)b;
    }
    __syncthreads();
#pragma unroll
    for (int k = 0; k < 8; ++k) {
        u32 s = (u32)(k * TWG + t);
        u32 v = reord[s];
        u32 b = rb8[s];
        u32 local = s - sc[b];
        pairs[((size_t)r << LOG_NPTS) + (size_t)b * 1024 + gb[b] + local] = v;
    }
}

// ---------- pass 6: per-bucket reorder, coalesced out_re write ----------
__global__ __launch_bounds__(256) void trans_write(const u32* __restrict__ pairs,
                                                   int* __restrict__ out_re) {
    __shared__ u32 buf[1024];
    int g = blockIdx.x;
    int r = g >> 8, b = g & 255;
    size_t base = ((size_t)r << LOG_NPTS) + (size_t)b * 1024;
#pragma unroll
    for (int k = 0; k < 4; ++k) {
        u32 v = pairs[base + (size_t)(k * 256 + threadIdx.x)];
        buf[v >> 18] = v & 0x3FFFFu;
    }
    __syncthreads();
#pragma unroll
    for (int k = 0; k < 4; ++k) {
        int j = k * 256 + threadIdx.x;
        out_re[base + (size_t)j] = (int)buf[j];
    }
}

extern "C" void kernel_launch(void* const* d_in, const int* in_sizes, int n_in,
                              void* d_out, int out_size, void* d_ws, size_t ws_size,
                              hipStream_t stream) {
    const float* z = (const float*)d_in[0];
    int* out_pa = (int*)d_out;
    int* out_re = out_pa + (size_t)BROWS * NPTS;

    char* ws = (char*)d_ws;
    u32* counts  = (u32*)(ws);                 // 32 KB
    u32* offsets = (u32*)(ws + (64u << 10));   // 32 KB
    u32* gcur    = (u32*)(ws + (128u << 10));  // 32 KB
    u32* tcur    = (u32*)(ws + (192u << 10));  // 32 KB
    ulonglong2* recKV = (ulonglong2*)(ws + (1u << 20));
    u32* pairs   = (u32*)recKV;                // 32 MB alias, used after fine_sort

    // fixed-region mode needs 1MB + 32*256*1280*16B = ~169 MB of ws
    size_t need = (1ull << 20) + (size_t)BROWS * CB * RCAP * sizeof(ulonglong2);
    int fixedMode = (ws_size >= need) ? 1 : 0;

    hipMemsetAsync(tcur, 0, (size_t)BROWS * CB * sizeof(u32), stream);
    if (fixedMode) {
        init_fixed<<<BROWS, 256, 0, stream>>>(gcur);
        ms_scatter<<<BROWS * 64, MWG, 0, stream>>>(z, gcur, recKV, 1);
        scan_fixed<<<BROWS, 256, 0, stream>>>(gcur, offsets, counts);
        fine_sort<<<BROWS * CB, 256, 0, stream>>>(recKV, offsets, counts, out_pa, 1);
    } else {
        hipMemsetAsync(counts, 0, (size_t)BROWS * CB * sizeof(u32), stream);
        hist_kernel<<<BROWS * 64, 256, 0, stream>>>(z, counts);
        scan_dense<<<BROWS, 256, 0, stream>>>(counts, offsets, gcur);
        ms_scatter<<<BROWS * 64, MWG, 0, stream>>>(z, gcur, recKV, 0);
        fine_sort<<<BROWS * CB, 256, 0, stream>>>(recKV, offsets, counts, out_pa, 0);
    }
    trans_ms<<<BROWS * 32, TWG, 0, stream>>>(out_pa, tcur, pairs);
    trans_write<<<BROWS * CB, 256, 0, stream>>>(pairs, out_re);
}

// Round 6
// 156.889 us; speedup vs baseline: 7.4808x; 1.0364x over previous
//
#include <hip/hip_runtime.h>
#include <stdint.h>

typedef unsigned int u32;
typedef unsigned long long u64;
typedef unsigned char u8;

#define BROWS 32
#define NPTS  262144           // 2^18 per row
#define LOG_NPTS 18
#define CB 256                 // coarse buckets per row
#define RCAP 1280              // fixed-region capacity per coarse bucket (mean 1024, +8 sigma)
#define ROWSTRIDE_FIX (CB * RCAP)   // 327680 records per row (fixed mode)
#define CCAP 1536              // LDS staging cap per coarse bucket
#define FB2 1024               // fine buckets per coarse bucket (mean 1)

// multisplit geometry: 1024 threads, 4 records/thread
#define MCH 4096
#define MWG 1024
// transpose multisplit geometry
#define TCH 8192
#define TWG 1024

// exact 18-bit grid: z0*2^18 is an exact f32 scaling; cb = g18>>10, fb = g18&1023
__device__ __forceinline__ u32 g18_of(float z0) {
    int b = (int)(z0 * 262144.0f);
    return (u32)(b < 0 ? 0 : (b > 262143 ? 262143 : b));
}

// ---------- dense-mode pass 1: coarse histogram ----------
__global__ __launch_bounds__(256) void hist_kernel(const float* __restrict__ z,
                                                   u32* __restrict__ counts) {
    __shared__ u32 h[CB];
    for (int i = threadIdx.x; i < CB; i += 256) h[i] = 0;
    __syncthreads();
    int r = blockIdx.x >> 6;
    int c = blockIdx.x & 63;
    size_t base = ((size_t)r << LOG_NPTS) + (size_t)c * 4096;
    for (int k = 0; k < 16; ++k) {
        float z0 = z[(base + (size_t)(k * 256 + threadIdx.x)) * 3];
        atomicAdd(&h[g18_of(z0) >> 10], 1u);
    }
    __syncthreads();
    for (int i = threadIdx.x; i < CB; i += 256)
        if (h[i]) atomicAdd(&counts[r * CB + i], h[i]);
}

// ---------- dense-mode pass 2: scan counts -> offsets, gcur ----------
__global__ __launch_bounds__(256) void scan_dense(const u32* __restrict__ counts,
                                                  u32* __restrict__ offsets,
                                                  u32* __restrict__ gcur) {
    int r = blockIdx.x, t = threadIdx.x;
    __shared__ u32 sc[CB];
    u32 v = counts[r * CB + t];
    sc[t] = v;
    __syncthreads();
    u32 own = v;
    for (int off = 1; off < CB; off <<= 1) {
        u32 a = (t >= off) ? sc[t - off] : 0;
        __syncthreads();
        sc[t] += a;
        __syncthreads();
    }
    u32 ex = sc[t] - own;
    offsets[r * CB + t] = ex;
    gcur[r * CB + t] = ex;
}

// ---------- fixed-mode: init region cursors ----------
__global__ void init_fixed(u32* __restrict__ gcur) {
    int i = blockIdx.x * 256 + threadIdx.x;   // 8192 entries
    gcur[i] = (u32)(i & 255) * RCAP;
}

// ---------- fixed-mode: post-scatter scan (cursors -> counts, offsets) ----------
__global__ __launch_bounds__(256) void scan_fixed(const u32* __restrict__ gcur,
                                                  u32* __restrict__ offsets,
                                                  u32* __restrict__ counts) {
    int r = blockIdx.x, t = threadIdx.x;
    __shared__ u32 sc[CB];
    u32 cnt = gcur[r * CB + t] - (u32)t * RCAP;
    if (cnt > RCAP) cnt = RCAP;
    counts[r * CB + t] = cnt;
    sc[t] = cnt;
    __syncthreads();
    u32 own = cnt;
    for (int off = 1; off < CB; off <<= 1) {
        u32 a = (t >= off) ? sc[t - off] : 0;
        __syncthreads();
        sc[t] += a;
        __syncthreads();
    }
    offsets[r * CB + t] = sc[t] - own;
}

// ---------- pass 3: multisplit scatter of 16B records ----------
__global__ __launch_bounds__(MWG) void ms_scatter(const float* __restrict__ z,
                                                  u32* __restrict__ gcur,
                                                  ulonglong2* __restrict__ recKV,
                                                  int fixedMode) {
    __shared__ u32 h[CB], sc[CB], gb[CB], wtot[4];
    __shared__ ulonglong2 rKV[MCH];
    int t = threadIdx.x;
    int r = blockIdx.x >> 6;           // 64 chunks of 4096 per row
    int c = blockIdx.x & 63;
    if (t < CB) h[t] = 0;
    __syncthreads();
    u64 mh[4], ml[4];
    u32 mpk[4];                         // (bucket<<16) | arrival
    size_t zbase = (((size_t)r << LOG_NPTS) + (size_t)c * MCH) * 3;
#pragma unroll
    for (int k = 0; k < 4; ++k) {
        u32 i = (u32)(c * MCH + k * MWG + t);
        const float* p = z + zbase + (size_t)(k * MWG + t) * 3;
        float f0 = p[0], f1 = p[1], f2 = p[2];
        u32 k0 = __float_as_uint(f0), k1 = __float_as_uint(f1), k2 = __float_as_uint(f2);
        mh[k] = ((u64)k0 << 32) | k1;
        ml[k] = ((u64)k2 << 32) | i;
        u32 b = g18_of(f0) >> 10;
        u32 arr = atomicAdd(&h[b], 1u);
        mpk[k] = (b << 16) | arr;
    }
    __syncthreads();
    // wave-shfl scan of 256 counts (waves 0-3, 64 each)
    u32 scan_s = 0, scan_v = 0;
    int lane = t & 63, wv = t >> 6;
    if (t < CB) {
        scan_v = h[t];
        scan_s = scan_v;
        for (int off = 1; off < 64; off <<= 1) {
            u32 o = __shfl_up(scan_s, off, 64);
            if (lane >= off) scan_s += o;
        }
        if (lane == 63) wtot[wv] = scan_s;
    }
    __syncthreads();
    if (t < CB) {
        u32 wbase = 0;
        if (wv > 0) wbase += wtot[0];
        if (wv > 1) wbase += wtot[1];
        if (wv > 2) wbase += wtot[2];
        sc[t] = wbase + scan_s - scan_v;         // exclusive prefix (LDS start)
        gb[t] = atomicAdd(&gcur[r * CB + t], h[t]);
    }
    __syncthreads();
#pragma unroll
    for (int k = 0; k < 4; ++k) {
        u32 b = mpk[k] >> 16, arr = mpk[k] & 0xFFFFu;
        u32 p = sc[b] + arr;
        rKV[p].x = mh[k];
        rKV[p].y = ml[k];
    }
    __syncthreads();
    size_t rowrec = fixedMode ? (size_t)r * ROWSTRIDE_FIX : ((size_t)r << LOG_NPTS);
#pragma unroll
    for (int k = 0; k < 4; ++k) {
        u32 s = (u32)(k * MWG + t);
        ulonglong2 v = rKV[s];
        u32 b = g18_of(__uint_as_float((u32)(v.x >> 32))) >> 10;
        u32 local = s - sc[b];
        u32 dst = gb[b] + local;
        if (!fixedMode || dst < b * (u32)RCAP + (u32)RCAP)
            recKV[rowrec + dst] = v;
    }
}

// ---------- pass 4: per-coarse-bucket rank sort (1024 fine buckets, mean 1) ----------
__global__ __launch_bounds__(256) void fine_sort(const ulonglong2* __restrict__ recKV,
                                                 const u32* __restrict__ offsets,
                                                 const u32* __restrict__ counts,
                                                 int* __restrict__ out_pa,
                                                 int fixedMode) {
    __shared__ ulonglong2 kv2[CCAP];
    __shared__ u32 fh[FB2], fex[FB2], wtot[4];
    int t = threadIdx.x;
    int g = blockIdx.x;
    int r = g >> 8;
    int cbk = g & 255;
    size_t rowrec = fixedMode ? (size_t)r * ROWSTRIDE_FIX : ((size_t)r << LOG_NPTS);
    u32 rdstart = fixedMode ? (u32)cbk * RCAP : offsets[g];
    u32 wrstart = offsets[g];
    u32 count = counts[g];
    u32 cap = fixedMode ? (u32)RCAP : (u32)CCAP;
    if (count > cap) count = cap;
    for (int i = t; i < FB2; i += 256) fh[i] = 0;
    __syncthreads();

    u64 rh[6], rl[6];
    u32 rpk[6];
#pragma unroll
    for (int k = 0; k < 6; ++k) {
        u32 s = (u32)t + (u32)k * 256u;
        rpk[k] = 0xFFFFFFFFu;
        if (s < count) {
            ulonglong2 rec = recKV[rowrec + rdstart + s];
            rh[k] = rec.x; rl[k] = rec.y;
            u32 fb = g18_of(__uint_as_float((u32)(rec.x >> 32))) & (FB2 - 1);
            u32 arr = atomicAdd(&fh[fb], 1u);
            rpk[k] = (fb << 16) | arr;
        }
    }
    __syncthreads();
    // two-level scan of 1024 counts (4 per thread)
    {
        u32 v0 = fh[4 * t], v1 = fh[4 * t + 1], v2 = fh[4 * t + 2], v3 = fh[4 * t + 3];
        u32 tsum = v0 + v1 + v2 + v3;
        u32 s = tsum;
        int lane = t & 63, w = t >> 6;
        for (int off = 1; off < 64; off <<= 1) {
            u32 o = __shfl_up(s, off, 64);
            if (lane >= off) s += o;
        }
        if (lane == 63) wtot[w] = s;
        __syncthreads();
        u32 wbase = 0;
        if (w > 0) wbase += wtot[0];
        if (w > 1) wbase += wtot[1];
        if (w > 2) wbase += wtot[2];
        u32 ex = wbase + s - tsum;
        fex[4 * t] = ex;
        fex[4 * t + 1] = ex + v0;
        fex[4 * t + 2] = ex + v0 + v1;
        fex[4 * t + 3] = ex + v0 + v1 + v2;
    }
    __syncthreads();
#pragma unroll
    for (int k = 0; k < 6; ++k) {
        if (rpk[k] != 0xFFFFFFFFu) {
            u32 fb = rpk[k] >> 16, arr = rpk[k] & 0xFFFFu;
            u32 p = fex[fb] + arr;
            kv2[p].x = rh[k];
            kv2[p].y = rl[k];
        }
    }
    __syncthreads();

    size_t orow = (size_t)r << LOG_NPTS;
#pragma unroll
    for (int k = 0; k < 6; ++k) {
        if (rpk[k] == 0xFFFFFFFFu) continue;
        u32 fb = rpk[k] >> 16;
        u32 cnt = fh[fb];
        u32 rank = 0;
        if (cnt > 1) {
            u32 base = fex[fb];
            for (u32 j = 0; j < cnt; ++j) {
                ulonglong2 b2 = kv2[base + j];
                rank += (b2.x < rh[k]) || (b2.x == rh[k] && b2.y < rl[k]);
            }
        }
        u32 pos = fex[fb] + rank;
        out_pa[orow + wrstart + pos] = (int)(u32)(rl[k] & 0x3FFFFu);
    }
}

// ---------- pass 5: multisplit-transpose of the permutation ----------
__global__ __launch_bounds__(TWG) void trans_ms(const int* __restrict__ out_pa,
                                                u32* __restrict__ tcur,
                                                u32* __restrict__ pairs) {
    __shared__ u32 h[CB], sc[CB], gb[CB], wtot[4];
    __shared__ u32 reord[TCH];
    __shared__ u8 rb8[TCH];
    int t = threadIdx.x;
    int r = blockIdx.x >> 5;           // 32 chunks of 8192 per row
    int c = blockIdx.x & 31;
    if (t < CB) h[t] = 0;
    __syncthreads();
    u32 mpk[8], mv[8];
#pragma unroll
    for (int k = 0; k < 8; ++k) {
        u32 p = (u32)(c * TCH + k * TWG + t);
        u32 si = (u32)out_pa[((size_t)r << LOG_NPTS) + p];
        u32 b = si >> 10;
        mv[k] = ((si & 1023u) << 18) | p;
        u32 arr = atomicAdd(&h[b], 1u);
        mpk[k] = (b << 16) | arr;
    }
    __syncthreads();
    u32 scan_s = 0, scan_v = 0;
    int lane = t & 63, wv = t >> 6;
    if (t < CB) {
        scan_v = h[t];
        scan_s = scan_v;
        for (int off = 1; off < 64; off <<= 1) {
            u32 o = __shfl_up(scan_s, off, 64);
            if (lane >= off) scan_s += o;
        }
        if (lane == 63) wtot[wv] = scan_s;
    }
    __syncthreads();
    if (t < CB) {
        u32 wbase = 0;
        if (wv > 0) wbase += wtot[0];
        if (wv > 1) wbase += wtot[1];
        if (wv > 2) wbase += wtot[2];
        sc[t] = wbase + scan_s - scan_v;
        gb[t] = atomicAdd(&tcur[r * CB + t], h[t]);
    }
    __syncthreads();
#pragma unroll
    for (int k = 0; k < 8; ++k) {
        u32 b = mpk[k] >> 16, arr = mpk[k] & 0xFFFFu;
        u32 p = sc[b] + arr;
        reord[p] = mv[k];
        rb8[p] = (u8)b;
    }
    __syncthreads();
#pragma unroll
    for (int k = 0; k < 8; ++k) {
        u32 s = (u32)(k * TWG + t);
        u32 v = reord[s];
        u32 b = rb8[s];
        u32 local = s - sc[b];
        pairs[((size_t)r << LOG_NPTS) + (size_t)b * 1024 + gb[b] + local] = v;
    }
}

// ---------- pass 6: per-bucket reorder, coalesced out_re write ----------
__global__ __launch_bounds__(256) void trans_write(const u32* __restrict__ pairs,
                                                   int* __restrict__ out_re) {
    __shared__ u32 buf[1024];
    int g = blockIdx.x;
    int r = g >> 8, b = g & 255;
    size_t base = ((size_t)r << LOG_NPTS) + (size_t)b * 1024;
#pragma unroll
    for (int k = 0; k < 4; ++k) {
        u32 v = pairs[base + (size_t)(k * 256 + threadIdx.x)];
        buf[v >> 18] = v & 0x3FFFFu;
    }
    __syncthreads();
#pragma unroll
    for (int k = 0; k < 4; ++k) {
        int j = k * 256 + threadIdx.x;
        out_re[base + (size_t)j] = (int)buf[j];
    }
}

extern "C" void kernel_launch(void* const* d_in, const int* in_sizes, int n_in,
                              void* d_out, int out_size, void* d_ws, size_t ws_size,
                              hipStream_t stream) {
    const float* z = (const float*)d_in[0];
    int* out_pa = (int*)d_out;
    int* out_re = out_pa + (size_t)BROWS * NPTS;

    char* ws = (char*)d_ws;
    u32* counts  = (u32*)(ws);                 // 32 KB
    u32* offsets = (u32*)(ws + (64u << 10));   // 32 KB
    u32* gcur    = (u32*)(ws + (128u << 10));  // 32 KB
    u32* tcur    = (u32*)(ws + (192u << 10));  // 32 KB
    ulonglong2* recKV = (ulonglong2*)(ws + (1u << 20));
    u32* pairs   = (u32*)recKV;                // 32 MB alias, used after fine_sort

    // fixed-region mode needs 1MB + 32*256*1280*16B = ~169 MB of ws
    size_t need = (1ull << 20) + (size_t)BROWS * CB * RCAP * sizeof(ulonglong2);
    int fixedMode = (ws_size >= need) ? 1 : 0;

    hipMemsetAsync(tcur, 0, (size_t)BROWS * CB * sizeof(u32), stream);
    if (fixedMode) {
        init_fixed<<<BROWS, 256, 0, stream>>>(gcur);
        ms_scatter<<<BROWS * 64, MWG, 0, stream>>>(z, gcur, recKV, 1);
        scan_fixed<<<BROWS, 256, 0, stream>>>(gcur, offsets, counts);
        fine_sort<<<BROWS * CB, 256, 0, stream>>>(recKV, offsets, counts, out_pa, 1);
    } else {
        hipMemsetAsync(counts, 0, (size_t)BROWS * CB * sizeof(u32), stream);
        hist_kernel<<<BROWS * 64, 256, 0, stream>>>(z, counts);
        scan_dense<<<BROWS, 256, 0, stream>>>(counts, offsets, gcur);
        ms_scatter<<<BROWS * 64, MWG, 0, stream>>>(z, gcur, recKV, 0);
        fine_sort<<<BROWS * CB, 256, 0, stream>>>(recKV, offsets, counts, out_pa, 0);
    }
    trans_ms<<<BROWS * 32, TWG, 0, stream>>>(out_pa, tcur, pairs);
    trans_write<<<BROWS * CB, 256, 0, stream>>>(pairs, out_re);
}